// Round 6
// baseline (474.928 us; speedup 1.0000x reference)
//
#include <hip/hip_runtime.h>
#include <math.h>

#define BB 4
#define VV 256
#define HH 128
#define NBI (BB*VV)      // 1024 (b,i) rows
#define NE  (NBI*VV)     // 262144 e-rows
#define BN_EPS 1e-5f

typedef _Float16 half8_ __attribute__((ext_vector_type(8)));
typedef float    floatx4 __attribute__((ext_vector_type(4)));
typedef unsigned uintx4  __attribute__((ext_vector_type(4)));

__device__ __forceinline__ float sigmoidf_(float v) {
    return 1.0f / (1.0f + __expf(-v));
}

// pack 2 fp32 -> 1 dword of 2 fp16 (RTZ) — single v_cvt_pkrtz_f16_f32
__device__ __forceinline__ unsigned pk(float x, float y) {
    auto h = __builtin_amdgcn_cvt_pkrtz(x, y);   // vector of 2 __fp16
    return __builtin_bit_cast(unsigned, h);
}

__device__ __forceinline__ float h2f(unsigned short u) {
    _Float16 h = __builtin_bit_cast(_Float16, u);
    return (float)h;
}

// ---------------------------------------------------------------------------
// K1: Uh/Vh/Ah/Bh = h @ W^T + b  (4 small GEMVs per row), plus Cw -> MFMA
// B-fragment packing (f16) into ws.
// Ah/Vh are written PRE-PERMUTED into the MFMA fragment layout:
//   avp[row*256 + hl*16 + ht]     = Ah[row][ht*16+hl]
//   avp[row*256 + hl*16 + 8 + ht] = Vh[row][ht*16+hl]
// so K2's epilogue reads each j-row's A/V values as 4 contiguous float4
// loads per lane (64 B/lane) instead of 16 scattered dwords.
// Cw packing layout: idx = ((ks*8 + ht)*64 + lane)*8 + j  holds
//   Cw[h][k] with h = ht*16 + (lane&15), k = ks*32 + (lane>>4)*8 + j
// ---------------------------------------------------------------------------
__global__ __launch_bounds__(128)
void k1_lin4(const float* __restrict__ h,
             const float* __restrict__ Uw, const float* __restrict__ Ub,
             const float* __restrict__ Vw, const float* __restrict__ Vb,
             const float* __restrict__ Aw, const float* __restrict__ Ab,
             const float* __restrict__ Bw, const float* __restrict__ Bb,
             const float* __restrict__ Cw,
             float* __restrict__ Uh, float* __restrict__ Bh,
             float* __restrict__ avp,
             unsigned short* __restrict__ cwp)
{
    __shared__ float sh[HH];
    int bi = blockIdx.x;
    int o  = threadIdx.x;

    if (bi < 128) {
        int idx  = bi*128 + o;
        int j    = idx & 7;
        int slot = idx >> 3;
        int lane = slot & 63;
        int tile = slot >> 6;       // ks*8 + ht
        int ht   = tile & 7;
        int ks   = tile >> 3;
        int k    = ks*32 + (lane >> 4)*8 + j;
        int hh   = ht*16 + (lane & 15);
        _Float16 hv = (_Float16)Cw[hh*HH + k];
        cwp[idx] = __builtin_bit_cast(unsigned short, hv);
    }

    sh[o] = h[bi*HH + o];
    __syncthreads();

    float su = Ub[o], sv = Vb[o], sa = Ab[o], sb = Bb[o];
    const float4* sh4 = (const float4*)sh;
    const float4* Uw4 = (const float4*)Uw;
    const float4* Vw4 = (const float4*)Vw;
    const float4* Aw4 = (const float4*)Aw;
    const float4* Bw4 = (const float4*)Bw;
    #pragma unroll 8
    for (int k4 = 0; k4 < 32; ++k4) {
        float4 hv = sh4[k4];
        float4 wu = Uw4[o*32 + k4];
        float4 wv = Vw4[o*32 + k4];
        float4 wa = Aw4[o*32 + k4];
        float4 wb = Bw4[o*32 + k4];
        su += hv.x*wu.x + hv.y*wu.y + hv.z*wu.z + hv.w*wu.w;
        sv += hv.x*wv.x + hv.y*wv.y + hv.z*wv.z + hv.w*wv.w;
        sa += hv.x*wa.x + hv.y*wa.y + hv.z*wa.z + hv.w*wa.w;
        sb += hv.x*wb.x + hv.y*wb.y + hv.z*wb.z + hv.w*wb.w;
    }
    Uh[bi*HH + o] = su;
    Bh[bi*HH + o] = sb;
    int hl = o & 15, ht = o >> 4;
    avp[bi*256 + hl*16 + ht]     = sa;
    avp[bi*256 + hl*16 + 8 + ht] = sv;
}

// ---------------------------------------------------------------------------
// K2: main fused pass, vmcnt-order-aware pipelined MFMA edition.
// One block per (b,i). 256 thr = 4 waves. No barriers in the main loop.
// Per half (16 j-rows x 128 h):
//   [AV prefetch (4u x 4 float4, fragment-layout)] -> [pack+MFMA consume L]
//   -> [issue next-half e loads] -> [epilogue u0..u3] -> [4 nt stores LAST].
// Rationale: vmcnt retires IN ORDER, so stores come after every load a wave
// will consume soon; AV + next-half e loads are all batch-issued and their
// latency hides under pack+MFMA / epilogue VALU.
// e_new stash: f16 fragment-permuted, one 16B nt-store per lane per j-row
// into the first 256B of each 512B out1 row slot.
//   stash short pos p = hl*8 + ht  <->  channel hh = ht*16 + hl
// C/D layout (m89/m91): h = lane&15 (+16*ht), j-row = (lane>>4)*4 + reg.
// ---------------------------------------------------------------------------
__global__ __launch_bounds__(256, 3)
void k2_main(const float* __restrict__ e,
             const float* __restrict__ x,
             const int*   __restrict__ graph,
             const unsigned short* __restrict__ cwp,
             const float* __restrict__ Cb,
             const float* __restrict__ dw, const float* __restrict__ db,
             const float* __restrict__ ew, const float* __restrict__ ebp,
             const float* __restrict__ Uh, const float* __restrict__ Bh,
             const float* __restrict__ avp,
             uintx4* __restrict__ stash,        // out1 region viewed as uintx4
             float* __restrict__ epart,         // [NBI][2][HH]
             float* __restrict__ hacc,          // [NBI][HH]
             float* __restrict__ xupd)          // [NBI][2]
{
    __shared__ unsigned short s_b[16384];   // 32 KB packed f16 B frags
    __shared__ float s_dist[256], s_dx[256], s_dy[256];
    __shared__ int   s_g[256];
    __shared__ float s_red[4*HH];

    int tid  = threadIdx.x;
    int bi   = blockIdx.x;
    int b    = bi >> 8;
    int lane = tid & 63;
    int w    = tid >> 6;
    int hl   = lane & 15;       // h within 16-wide tile
    int q    = lane >> 4;       // quad: k-octet for A frags, j-subrow for C

    // stage packed B: 32768 B = 2048 int4, 8 per thread, coalesced
    {
        const int4* src = (const int4*)cwp;
        int4* dst = (int4*)s_b;
        #pragma unroll
        for (int it = 0; it < 8; ++it) dst[tid + it*256] = src[tid + it*256];
    }

    float xi0 = x[bi*2 + 0], xi1 = x[bi*2 + 1];
    {   // stage geometry + graph for ALL 256 j once
        int j = tid;
        float xj0 = x[(b*VV + j)*2 + 0], xj1 = x[(b*VV + j)*2 + 1];
        float dx = xi0 - xj0, dy = xi1 - xj1;
        float d2 = dx*dx + dy*dy;
        s_dx[j] = dx; s_dy[j] = dy;
        s_dist[j] = (d2 > 0.f) ? sqrtf(d2) : 0.f;
        s_g[j] = graph[(size_t)bi*VV + j];
    }

    // per-lane per-h constants (h = ht*16 + hl)
    float pre[8], dwv[8], ewv[8];
    #pragma unroll
    for (int ht = 0; ht < 8; ++ht) {
        int hh = ht*16 + hl;
        pre[ht] = Bh[bi*HH + hh] + Cb[hh] + db[hh];
        dwv[ht] = dw[hh];
        ewv[ht] = ew[hh];
    }
    float ebv = ebp[0];

    __syncthreads();        // the ONLY barrier before the final reduction

    float ssum[8] = {0,0,0,0,0,0,0,0};
    float ssq [8] = {0,0,0,0,0,0,0,0};
    float hsum[8] = {0,0,0,0,0,0,0,0};
    float xa0 = 0.f, xa1 = 0.f;

    // prologue: issue e loads for half 0 (j0 = w*32)
    float4 L[8];
    {
        const float* eA = e + ((size_t)bi*VV + w*32 + hl)*HH + q*8;
        #pragma unroll
        for (int ks = 0; ks < 4; ++ks) {
            L[2*ks]   = *(const float4*)(eA + ks*32);
            L[2*ks+1] = *(const float4*)(eA + ks*32 + 4);
        }
    }

    #pragma unroll
    for (int ch = 0; ch < 4; ++ch) {        // ch = chunk*2 + half
        int chunk = ch >> 1, half = ch & 1;
        int j0 = chunk*128 + w*32 + half*16;
        int jb = j0 + q*4;

        // ---- AV prefetch: 4 contiguous float4 per u (fragment layout) ----
        floatx4 AV[4][4];
        #pragma unroll
        for (int u = 0; u < 4; ++u) {
            const floatx4* ab =
                (const floatx4*)(avp + ((size_t)(b*VV) + jb + u)*256 + hl*16);
            AV[u][0] = ab[0]; AV[u][1] = ab[1];
            AV[u][2] = ab[2]; AV[u][3] = ab[3];
        }

        // ---- pack + MFMA (consumes L; L regs dead afterwards) ----
        floatx4 acc[8];
        #pragma unroll
        for (int ht = 0; ht < 8; ++ht) acc[ht] = (floatx4){0.f,0.f,0.f,0.f};

        #pragma unroll
        for (int ks = 0; ks < 4; ++ks) {
            union { half8_ h; unsigned u[4]; } a;
            a.u[0] = pk(L[2*ks].x,   L[2*ks].y);
            a.u[1] = pk(L[2*ks].z,   L[2*ks].w);
            a.u[2] = pk(L[2*ks+1].x, L[2*ks+1].y);
            a.u[3] = pk(L[2*ks+1].z, L[2*ks+1].w);
            #pragma unroll
            for (int ht = 0; ht < 8; ++ht) {
                half8_ bf = *(const half8_*)(s_b + ((size_t)((ks*8 + ht)*64 + lane))*8);
                acc[ht] = __builtin_amdgcn_mfma_f32_16x16x32_f16(a.h, bf, acc[ht], 0, 0, 0);
            }
        }

        // ---- issue next half's e loads (hidden under epilogue) ----
        if (ch < 3) {
            int chn = ch + 1;
            int j0n = (chn >> 1)*128 + w*32 + (chn & 1)*16;
            const float* eA = e + ((size_t)bi*VV + j0n + hl)*HH + q*8;
            #pragma unroll
            for (int ks = 0; ks < 4; ++ks) {
                L[2*ks]   = *(const float4*)(eA + ks*32);
                L[2*ks+1] = *(const float4*)(eA + ks*32 + 4);
            }
        }

        // ---- epilogue over this half's 4 j-rows owned by this quad ----
        uintx4 st[4];
        #pragma unroll
        for (int u = 0; u < 4; ++u) {
            int j = jb + u;
            float Av[8], Vv[8];
            #pragma unroll
            for (int ht = 0; ht < 4; ++ht) {
                Av[ht]   = AV[u][0][ht];
                Av[ht+4] = AV[u][1][ht];
                Vv[ht]   = AV[u][2][ht];
                Vv[ht+4] = AV[u][3][ht];
            }

            float dist = s_dist[j], dx = s_dx[j], dy = s_dy[j];
            int g = s_g[j];

            float en[8];
            float padot = 0.f;
            #pragma unroll
            for (int ht = 0; ht < 8; ++ht) {
                float v = acc[ht][u] + Av[ht] + pre[ht] + dist*dwv[ht];
                en[ht] = v;
                ssum[ht] += v;
                ssq[ht]  += v*v;
                padot    += v*ewv[ht];
            }
            if (g != 1) {
                #pragma unroll
                for (int ht = 0; ht < 8; ++ht)
                    hsum[ht] += sigmoidf_(en[ht]) * Vv[ht];
            }

            st[u].x = pk(en[0], en[1]);
            st[u].y = pk(en[2], en[3]);
            st[u].z = pk(en[4], en[5]);
            st[u].w = pk(en[6], en[7]);

            padot += __shfl_xor(padot, 1);
            padot += __shfl_xor(padot, 2);
            padot += __shfl_xor(padot, 4);
            padot += __shfl_xor(padot, 8);
            if (hl == 0) {
                float pa = sigmoidf_(padot + ebv);
                xa0 += pa * dx;
                xa1 += pa * dy;
            }
        }

        // ---- all stores LAST (nt: no RFO, no L2 pollution) ----
        #pragma unroll
        for (int u = 0; u < 4; ++u)
            __builtin_nontemporal_store(st[u],
                &stash[((size_t)bi*VV + jb + u)*32 + hl]);
    }

    // ---- cross-quad reduce (lanes sharing hl, different j-subrows) ----
    #pragma unroll
    for (int ht = 0; ht < 8; ++ht) {
        ssum[ht] += __shfl_xor(ssum[ht], 16); ssum[ht] += __shfl_xor(ssum[ht], 32);
        ssq[ht]  += __shfl_xor(ssq[ht],  16); ssq[ht]  += __shfl_xor(ssq[ht],  32);
        hsum[ht] += __shfl_xor(hsum[ht], 16); hsum[ht] += __shfl_xor(hsum[ht], 32);
    }

    __syncthreads();
    if (lane < 16) {
        #pragma unroll
        for (int ht = 0; ht < 8; ++ht) s_red[w*HH + ht*16 + lane] = ssum[ht];
    }
    __syncthreads();
    if (tid < HH)
        epart[(size_t)bi*2*HH + tid] =
            s_red[tid] + s_red[HH + tid] + s_red[2*HH + tid] + s_red[3*HH + tid];
    __syncthreads();
    if (lane < 16) {
        #pragma unroll
        for (int ht = 0; ht < 8; ++ht) s_red[w*HH + ht*16 + lane] = ssq[ht];
    }
    __syncthreads();
    if (tid < HH)
        epart[(size_t)bi*2*HH + HH + tid] =
            s_red[tid] + s_red[HH + tid] + s_red[2*HH + tid] + s_red[3*HH + tid];
    __syncthreads();
    if (lane < 16) {
        #pragma unroll
        for (int ht = 0; ht < 8; ++ht) s_red[w*HH + ht*16 + lane] = hsum[ht];
    }
    __syncthreads();
    if (tid < HH)
        hacc[bi*HH + tid] = Uh[bi*HH + tid] +
            s_red[tid] + s_red[HH + tid] + s_red[2*HH + tid] + s_red[3*HH + tid];
    __syncthreads();
    if (hl == 0) { s_red[w*4 + q] = xa0; s_red[16 + w*4 + q] = xa1; }
    __syncthreads();
    if (tid == 0) {
        float sx = 0.f, sy = 0.f;
        #pragma unroll
        for (int t = 0; t < 16; ++t) { sx += s_red[t]; sy += s_red[16 + t]; }
        xupd[bi*2 + 0] = sx;
        xupd[bi*2 + 1] = sy;
    }
}

// ---------------------------------------------------------------------------
// K3: finalize BN stats -> per-channel scale/shift for e and h
// ---------------------------------------------------------------------------
__global__ __launch_bounds__(256)
void k3_stats(const float* __restrict__ epart, const float* __restrict__ hacc,
              const float* __restrict__ gamma_e, const float* __restrict__ beta_e,
              const float* __restrict__ gamma_h, const float* __restrict__ beta_h,
              float* __restrict__ coefs)
{
    __shared__ float rs[256], rq[256];
    int c = blockIdx.x, tid = threadIdx.x;
    float s = 0, q = 0;
    if (c < HH) {
        for (int r = tid; r < NBI; r += 256) {
            s += epart[(size_t)r*2*HH + c];
            q += epart[(size_t)r*2*HH + HH + c];
        }
    } else {
        int hh = c - HH;
        for (int r = tid; r < NBI; r += 256) {
            float v = hacc[r*HH + hh];
            s += v; q += v*v;
        }
    }
    rs[tid] = s; rq[tid] = q;
    __syncthreads();
    for (int off = 128; off > 0; off >>= 1) {
        if (tid < off) { rs[tid] += rs[tid+off]; rq[tid] += rq[tid+off]; }
        __syncthreads();
    }
    if (tid == 0) {
        float n = (c < HH) ? (float)NE : (float)NBI;
        float mean = rs[0] / n;
        float var  = rq[0] / n - mean*mean;
        int hh; float g, be;
        if (c < HH) { hh = c;      g = gamma_e[hh]; be = beta_e[hh]; }
        else        { hh = c - HH; g = gamma_h[hh]; be = beta_h[hh]; }
        float scale = g * rsqrtf(var + BN_EPS);
        float shift = be - mean*scale;
        if (c < HH) { coefs[hh]        = scale; coefs[HH + hh]   = shift; }
        else        { coefs[2*HH + hh] = scale; coefs[3*HH + hh] = shift; }
    }
}

// ---------------------------------------------------------------------------
// K4: out1 = e + relu(bn(e_new)), reading the f16 fragment-permuted stash
// (first 256B of each 512B out1 row) through an LDS re-permute.
// One block per 64-row tile (4096 tiles). Also (first blocks) h and x outs.
// nt loads for the stash (never re-read), nt stores for out1 (never re-read).
// LDS row stride = 144 shorts (288B): r and r+1 land 8 banks apart -> <=4-way.
// ---------------------------------------------------------------------------
__global__ __launch_bounds__(256)
void k4_eout(const float* __restrict__ e, const float* __restrict__ coefs,
             const float* __restrict__ h, const float* __restrict__ x,
             const float* __restrict__ hacc, const float* __restrict__ xupd,
             const float* __restrict__ cp,
             float* __restrict__ out0, float* __restrict__ out2,
             float* __restrict__ out1)
{
    __shared__ unsigned short s_t[64*144];   // 18432 B
    int tid = threadIdx.x;
    int gid = blockIdx.x*256 + tid;
    if (gid < NBI*HH) {
        int hh = gid & 127;
        float v = hacc[gid]*coefs[2*HH + hh] + coefs[3*HH + hh];
        out0[gid] = h[gid] + fmaxf(v, 0.f);
        if (gid < NBI*2) out2[gid] = x[gid] + cp[0]*xupd[gid];
    }

    size_t r0 = (size_t)blockIdx.x * 64;
    const uintx4* sp = (const uintx4*)out1;
    #pragma unroll
    for (int it = 0; it < 4; ++it) {
        int rr = it*16 + (tid >> 4);
        int sg = tid & 15;
        uintx4 v = __builtin_nontemporal_load(&sp[(r0 + rr)*32 + sg]);
        *(uintx4*)(s_t + rr*144 + sg*8) = v;
    }
    __syncthreads();

    const float4* e4  = (const float4*)e;
    floatx4* o4       = (floatx4*)out1;
    const float4* sc4 = (const float4*)coefs;        // scale_e
    const float4* sh4 = (const float4*)(coefs + HH); // shift_e
    #pragma unroll
    for (int k = 0; k < 8; ++k) {
        int f  = k*256 + tid;        // 0..2047 float4s in tile
        int r  = f >> 5;
        int c4 = f & 31;
        size_t gi = (r0 + r)*32 + c4;
        float4 ev = e4[gi];
        float4 sc = sc4[c4], sh = sh4[c4];
        const unsigned short* row = s_t + r*144;
        int cc = c4*4;
        int pb = (cc & 15)*8 + (cc >> 4);   // p = (hh&15)*8 + (hh>>4)
        float4 en;
        en.x = h2f(row[pb]);
        en.y = h2f(row[pb + 8]);
        en.z = h2f(row[pb + 16]);
        en.w = h2f(row[pb + 24]);
        floatx4 rr;
        rr.x = ev.x + fmaxf(en.x*sc.x + sh.x, 0.f);
        rr.y = ev.y + fmaxf(en.y*sc.y + sh.y, 0.f);
        rr.z = ev.z + fmaxf(en.z*sc.z + sh.z, 0.f);
        rr.w = ev.w + fmaxf(en.w*sc.w + sh.w, 0.f);
        __builtin_nontemporal_store(rr, &o4[gi]);
    }
}

// ---------------------------------------------------------------------------
extern "C" void kernel_launch(void* const* d_in, const int* in_sizes, int n_in,
                              void* d_out, int out_size, void* d_ws, size_t ws_size,
                              hipStream_t stream)
{
    (void)in_sizes; (void)n_in; (void)out_size; (void)ws_size;
    const float* h     = (const float*)d_in[0];
    const float* e     = (const float*)d_in[1];
    const float* x     = (const float*)d_in[2];
    const int*   graph = (const int*)d_in[3];
    const float* Uw = (const float*)d_in[4];
    const float* Ub = (const float*)d_in[5];
    const float* Vw = (const float*)d_in[6];
    const float* Vb = (const float*)d_in[7];
    const float* Aw = (const float*)d_in[8];
    const float* Ab = (const float*)d_in[9];
    const float* Bw = (const float*)d_in[10];
    const float* Bbv = (const float*)d_in[11];
    const float* Cw = (const float*)d_in[12];
    const float* Cb = (const float*)d_in[13];
    const float* dw = (const float*)d_in[14];
    const float* db = (const float*)d_in[15];
    const float* ew = (const float*)d_in[16];
    const float* eb = (const float*)d_in[17];
    const float* c  = (const float*)d_in[18];
    const float* gamma_h = (const float*)d_in[19];
    const float* beta_h  = (const float*)d_in[20];
    const float* gamma_e = (const float*)d_in[21];
    const float* beta_e  = (const float*)d_in[22];

    float* out0 = (float*)d_out;
    float* out1 = out0 + NBI*HH;
    float* out2 = out1 + (size_t)NE*HH;

    float* ws    = (float*)d_ws;
    float* Uh    = ws;                      // NBI*HH
    float* Bh    = Uh + NBI*HH;             // NBI*HH
    float* avp   = Bh + NBI*HH;             // NBI*256 (A/V fragment-permuted)
    float* hacc  = avp + (size_t)NBI*256;   // NBI*HH
    float* epart = hacc + NBI*HH;           // NBI*2*HH
    float* xupd  = epart + (size_t)NBI*2*HH;
    float* coefs = xupd + NBI*2;
    unsigned short* cwp = (unsigned short*)(coefs + 4*HH);  // 16384 f16

    k1_lin4<<<NBI, 128, 0, stream>>>(h, Uw, Ub, Vw, Vb, Aw, Ab, Bw, Bbv, Cw,
                                     Uh, Bh, avp, cwp);
    k2_main<<<NBI, 256, 0, stream>>>(e, x, graph, cwp, Cb, dw, db, ew, eb,
                                     Uh, Bh, avp, (uintx4*)out1,
                                     epart, hacc, xupd);
    k3_stats<<<2*HH, 256, 0, stream>>>(epart, hacc, gamma_e, beta_e,
                                       gamma_h, beta_h, coefs);
    k4_eout<<<NE/64, 256, 0, stream>>>(e, coefs, h, x, hacc, xupd, c,
                                       out0, out2, out1);
}

// Round 7
// 384.990 us; speedup vs baseline: 1.2336x; 1.2336x over previous
//
#include <hip/hip_runtime.h>
#include <math.h>

#define BB 4
#define VV 256
#define HH 128
#define NBI (BB*VV)      // 1024 (b,i) rows
#define NE  (NBI*VV)     // 262144 e-rows
#define BN_EPS 1e-5f

typedef _Float16 half8_ __attribute__((ext_vector_type(8)));
typedef float    floatx4 __attribute__((ext_vector_type(4)));
typedef unsigned uintx4  __attribute__((ext_vector_type(4)));

__device__ __forceinline__ float sigmoidf_(float v) {
    return 1.0f / (1.0f + __expf(-v));
}

// pack 2 fp32 -> 1 dword of 2 fp16 (RTZ) — single v_cvt_pkrtz_f16_f32
__device__ __forceinline__ unsigned pk(float x, float y) {
    auto h = __builtin_amdgcn_cvt_pkrtz(x, y);   // vector of 2 __fp16
    return __builtin_bit_cast(unsigned, h);
}

__device__ __forceinline__ float h2f(unsigned short u) {
    _Float16 h = __builtin_bit_cast(_Float16, u);
    return (float)h;
}

// ---------------------------------------------------------------------------
// K1: Uh/Vh/Ah/Bh = h @ W^T + b  (4 small GEMVs per row), plus Cw -> MFMA
// B-fragment packing (f16) into ws.
// Ah/Vh are written PRE-PERMUTED into the MFMA fragment layout:
//   avp[row*256 + hl*16 + ht]     = Ah[row][ht*16+hl]
//   avp[row*256 + hl*16 + 8 + ht] = Vh[row][ht*16+hl]
// so K2's epilogue reads each j-row's A/V values as 4 contiguous float4
// loads per lane (64 B/lane) instead of 16 scattered dwords.
// Cw packing layout: idx = ((ks*8 + ht)*64 + lane)*8 + j  holds
//   Cw[h][k] with h = ht*16 + (lane&15), k = ks*32 + (lane>>4)*8 + j
// ---------------------------------------------------------------------------
__global__ __launch_bounds__(128)
void k1_lin4(const float* __restrict__ h,
             const float* __restrict__ Uw, const float* __restrict__ Ub,
             const float* __restrict__ Vw, const float* __restrict__ Vb,
             const float* __restrict__ Aw, const float* __restrict__ Ab,
             const float* __restrict__ Bw, const float* __restrict__ Bb,
             const float* __restrict__ Cw,
             float* __restrict__ Uh, float* __restrict__ Bh,
             float* __restrict__ avp,
             unsigned short* __restrict__ cwp)
{
    __shared__ float sh[HH];
    int bi = blockIdx.x;
    int o  = threadIdx.x;

    if (bi < 128) {
        int idx  = bi*128 + o;
        int j    = idx & 7;
        int slot = idx >> 3;
        int lane = slot & 63;
        int tile = slot >> 6;       // ks*8 + ht
        int ht   = tile & 7;
        int ks   = tile >> 3;
        int k    = ks*32 + (lane >> 4)*8 + j;
        int hh   = ht*16 + (lane & 15);
        _Float16 hv = (_Float16)Cw[hh*HH + k];
        cwp[idx] = __builtin_bit_cast(unsigned short, hv);
    }

    sh[o] = h[bi*HH + o];
    __syncthreads();

    float su = Ub[o], sv = Vb[o], sa = Ab[o], sb = Bb[o];
    const float4* sh4 = (const float4*)sh;
    const float4* Uw4 = (const float4*)Uw;
    const float4* Vw4 = (const float4*)Vw;
    const float4* Aw4 = (const float4*)Aw;
    const float4* Bw4 = (const float4*)Bw;
    #pragma unroll 8
    for (int k4 = 0; k4 < 32; ++k4) {
        float4 hv = sh4[k4];
        float4 wu = Uw4[o*32 + k4];
        float4 wv = Vw4[o*32 + k4];
        float4 wa = Aw4[o*32 + k4];
        float4 wb = Bw4[o*32 + k4];
        su += hv.x*wu.x + hv.y*wu.y + hv.z*wu.z + hv.w*wu.w;
        sv += hv.x*wv.x + hv.y*wv.y + hv.z*wv.z + hv.w*wv.w;
        sa += hv.x*wa.x + hv.y*wa.y + hv.z*wa.z + hv.w*wa.w;
        sb += hv.x*wb.x + hv.y*wb.y + hv.z*wb.z + hv.w*wb.w;
    }
    Uh[bi*HH + o] = su;
    Bh[bi*HH + o] = sb;
    int hl = o & 15, ht = o >> 4;
    avp[bi*256 + hl*16 + ht]     = sa;
    avp[bi*256 + hl*16 + 8 + ht] = sv;
}

// ---------------------------------------------------------------------------
// K2: main fused pass — EXACT round-4 structure (85 us, VGPR 128, no spills)
// with one change: epilogue A/V loads come from the fragment-permuted avp as
// contiguous float4s (4 per j-row) instead of 16 scattered dwords per j-row.
// Live-range shape is IDENTICAL to round 4: u0/u1 hoisted (32 regs) before
// next-half e-issue; u2/u3 loaded inline (short-lived). launch_bounds(256,2).
// Per half (16 j-rows x 128 h):
//   [pack+MFMA consume L] -> [hoist AV u0,u1 (8 float4)] ->
//   [issue next-half e loads] -> [epilogue u0..u3] -> [4 nt stores LAST].
// vmcnt retires IN ORDER: stores come after every load a wave consumes soon.
// e_new stash: f16 fragment-permuted, one 16B nt-store per lane per j-row
// into the first 256B of each 512B out1 row slot.
//   stash short pos p = hl*8 + ht  <->  channel hh = ht*16 + hl
// C/D layout (m89/m91): h = lane&15 (+16*ht), j-row = (lane>>4)*4 + reg.
// ---------------------------------------------------------------------------
__global__ __launch_bounds__(256, 2)
void k2_main(const float* __restrict__ e,
             const float* __restrict__ x,
             const int*   __restrict__ graph,
             const unsigned short* __restrict__ cwp,
             const float* __restrict__ Cb,
             const float* __restrict__ dw, const float* __restrict__ db,
             const float* __restrict__ ew, const float* __restrict__ ebp,
             const float* __restrict__ Uh, const float* __restrict__ Bh,
             const float* __restrict__ avp,
             uintx4* __restrict__ stash,        // out1 region viewed as uintx4
             float* __restrict__ epart,         // [NBI][2][HH]
             float* __restrict__ hacc,          // [NBI][HH]
             float* __restrict__ xupd)          // [NBI][2]
{
    __shared__ unsigned short s_b[16384];   // 32 KB packed f16 B frags
    __shared__ float s_dist[256], s_dx[256], s_dy[256];
    __shared__ int   s_g[256];
    __shared__ float s_red[4*HH];

    int tid  = threadIdx.x;
    int bi   = blockIdx.x;
    int b    = bi >> 8;
    int lane = tid & 63;
    int w    = tid >> 6;
    int hl   = lane & 15;       // h within 16-wide tile
    int q    = lane >> 4;       // quad: k-octet for A frags, j-subrow for C

    // stage packed B: 32768 B = 2048 int4, 8 per thread, coalesced
    {
        const int4* src = (const int4*)cwp;
        int4* dst = (int4*)s_b;
        #pragma unroll
        for (int it = 0; it < 8; ++it) dst[tid + it*256] = src[tid + it*256];
    }

    float xi0 = x[bi*2 + 0], xi1 = x[bi*2 + 1];
    {   // stage geometry + graph for ALL 256 j once
        int j = tid;
        float xj0 = x[(b*VV + j)*2 + 0], xj1 = x[(b*VV + j)*2 + 1];
        float dx = xi0 - xj0, dy = xi1 - xj1;
        float d2 = dx*dx + dy*dy;
        s_dx[j] = dx; s_dy[j] = dy;
        s_dist[j] = (d2 > 0.f) ? sqrtf(d2) : 0.f;
        s_g[j] = graph[(size_t)bi*VV + j];
    }

    // per-lane per-h constants (h = ht*16 + hl)
    float pre[8], dwv[8], ewv[8];
    #pragma unroll
    for (int ht = 0; ht < 8; ++ht) {
        int hh = ht*16 + hl;
        pre[ht] = Bh[bi*HH + hh] + Cb[hh] + db[hh];
        dwv[ht] = dw[hh];
        ewv[ht] = ew[hh];
    }
    float ebv = ebp[0];

    __syncthreads();        // the ONLY barrier before the final reduction

    float ssum[8] = {0,0,0,0,0,0,0,0};
    float ssq [8] = {0,0,0,0,0,0,0,0};
    float hsum[8] = {0,0,0,0,0,0,0,0};
    float xa0 = 0.f, xa1 = 0.f;

    // prologue: issue e loads for half 0 (j0 = w*32)
    float4 L[8];
    {
        const float* eA = e + ((size_t)bi*VV + w*32 + hl)*HH + q*8;
        #pragma unroll
        for (int ks = 0; ks < 4; ++ks) {
            L[2*ks]   = *(const float4*)(eA + ks*32);
            L[2*ks+1] = *(const float4*)(eA + ks*32 + 4);
        }
    }

    #pragma unroll
    for (int ch = 0; ch < 4; ++ch) {        // ch = chunk*2 + half
        int chunk = ch >> 1, half = ch & 1;
        int j0 = chunk*128 + w*32 + half*16;
        int jb = j0 + q*4;

        // ---- pack + MFMA (consumes L; L regs dead afterwards) ----
        floatx4 acc[8];
        #pragma unroll
        for (int ht = 0; ht < 8; ++ht) acc[ht] = (floatx4){0.f,0.f,0.f,0.f};

        #pragma unroll
        for (int ks = 0; ks < 4; ++ks) {
            union { half8_ h; unsigned u[4]; } a;
            a.u[0] = pk(L[2*ks].x,   L[2*ks].y);
            a.u[1] = pk(L[2*ks].z,   L[2*ks].w);
            a.u[2] = pk(L[2*ks+1].x, L[2*ks+1].y);
            a.u[3] = pk(L[2*ks+1].z, L[2*ks+1].w);
            #pragma unroll
            for (int ht = 0; ht < 8; ++ht) {
                half8_ bf = *(const half8_*)(s_b + ((size_t)((ks*8 + ht)*64 + lane))*8);
                acc[ht] = __builtin_amdgcn_mfma_f32_16x16x32_f16(a.h, bf, acc[ht], 0, 0, 0);
            }
        }

        // ---- hoist AV for u=0,1 BEFORE next-half load issue (8 float4) ----
        floatx4 AVh[2][4];
        #pragma unroll
        for (int u = 0; u < 2; ++u) {
            const floatx4* ab =
                (const floatx4*)(avp + ((size_t)(b*VV) + jb + u)*256 + hl*16);
            AVh[u][0] = ab[0]; AVh[u][1] = ab[1];
            AVh[u][2] = ab[2]; AVh[u][3] = ab[3];
        }

        // ---- issue next half's e loads (hidden under epilogue) ----
        if (ch < 3) {
            int chn = ch + 1;
            int j0n = (chn >> 1)*128 + w*32 + (chn & 1)*16;
            const float* eA = e + ((size_t)bi*VV + j0n + hl)*HH + q*8;
            #pragma unroll
            for (int ks = 0; ks < 4; ++ks) {
                L[2*ks]   = *(const float4*)(eA + ks*32);
                L[2*ks+1] = *(const float4*)(eA + ks*32 + 4);
            }
        }

        // ---- epilogue over this half's 4 j-rows owned by this quad ----
        uintx4 st[4];
        #pragma unroll
        for (int u = 0; u < 4; ++u) {
            int j = jb + u;
            float Av[8], Vv[8];
            if (u < 2) {
                #pragma unroll
                for (int ht = 0; ht < 4; ++ht) {
                    Av[ht]   = AVh[u][0][ht];
                    Av[ht+4] = AVh[u][1][ht];
                    Vv[ht]   = AVh[u][2][ht];
                    Vv[ht+4] = AVh[u][3][ht];
                }
            } else {
                const floatx4* ab =
                    (const floatx4*)(avp + ((size_t)(b*VV) + j)*256 + hl*16);
                floatx4 a0 = ab[0], a1 = ab[1], v0 = ab[2], v1 = ab[3];
                #pragma unroll
                for (int ht = 0; ht < 4; ++ht) {
                    Av[ht]   = a0[ht];
                    Av[ht+4] = a1[ht];
                    Vv[ht]   = v0[ht];
                    Vv[ht+4] = v1[ht];
                }
            }

            float dist = s_dist[j], dx = s_dx[j], dy = s_dy[j];
            int g = s_g[j];

            float en[8];
            float padot = 0.f;
            #pragma unroll
            for (int ht = 0; ht < 8; ++ht) {
                float v = acc[ht][u] + Av[ht] + pre[ht] + dist*dwv[ht];
                en[ht] = v;
                ssum[ht] += v;
                ssq[ht]  += v*v;
                padot    += v*ewv[ht];
            }
            if (g != 1) {
                #pragma unroll
                for (int ht = 0; ht < 8; ++ht)
                    hsum[ht] += sigmoidf_(en[ht]) * Vv[ht];
            }

            st[u].x = pk(en[0], en[1]);
            st[u].y = pk(en[2], en[3]);
            st[u].z = pk(en[4], en[5]);
            st[u].w = pk(en[6], en[7]);

            padot += __shfl_xor(padot, 1);
            padot += __shfl_xor(padot, 2);
            padot += __shfl_xor(padot, 4);
            padot += __shfl_xor(padot, 8);
            if (hl == 0) {
                float pa = sigmoidf_(padot + ebv);
                xa0 += pa * dx;
                xa1 += pa * dy;
            }
        }

        // ---- all stores LAST (nt: no RFO, no L2 pollution) ----
        #pragma unroll
        for (int u = 0; u < 4; ++u)
            __builtin_nontemporal_store(st[u],
                &stash[((size_t)bi*VV + jb + u)*32 + hl]);
    }

    // ---- cross-quad reduce (lanes sharing hl, different j-subrows) ----
    #pragma unroll
    for (int ht = 0; ht < 8; ++ht) {
        ssum[ht] += __shfl_xor(ssum[ht], 16); ssum[ht] += __shfl_xor(ssum[ht], 32);
        ssq[ht]  += __shfl_xor(ssq[ht],  16); ssq[ht]  += __shfl_xor(ssq[ht],  32);
        hsum[ht] += __shfl_xor(hsum[ht], 16); hsum[ht] += __shfl_xor(hsum[ht], 32);
    }

    __syncthreads();
    if (lane < 16) {
        #pragma unroll
        for (int ht = 0; ht < 8; ++ht) s_red[w*HH + ht*16 + lane] = ssum[ht];
    }
    __syncthreads();
    if (tid < HH)
        epart[(size_t)bi*2*HH + tid] =
            s_red[tid] + s_red[HH + tid] + s_red[2*HH + tid] + s_red[3*HH + tid];
    __syncthreads();
    if (lane < 16) {
        #pragma unroll
        for (int ht = 0; ht < 8; ++ht) s_red[w*HH + ht*16 + lane] = ssq[ht];
    }
    __syncthreads();
    if (tid < HH)
        epart[(size_t)bi*2*HH + HH + tid] =
            s_red[tid] + s_red[HH + tid] + s_red[2*HH + tid] + s_red[3*HH + tid];
    __syncthreads();
    if (lane < 16) {
        #pragma unroll
        for (int ht = 0; ht < 8; ++ht) s_red[w*HH + ht*16 + lane] = hsum[ht];
    }
    __syncthreads();
    if (tid < HH)
        hacc[bi*HH + tid] = Uh[bi*HH + tid] +
            s_red[tid] + s_red[HH + tid] + s_red[2*HH + tid] + s_red[3*HH + tid];
    __syncthreads();
    if (hl == 0) { s_red[w*4 + q] = xa0; s_red[16 + w*4 + q] = xa1; }
    __syncthreads();
    if (tid == 0) {
        float sx = 0.f, sy = 0.f;
        #pragma unroll
        for (int t = 0; t < 16; ++t) { sx += s_red[t]; sy += s_red[16 + t]; }
        xupd[bi*2 + 0] = sx;
        xupd[bi*2 + 1] = sy;
    }
}

// ---------------------------------------------------------------------------
// K3: finalize BN stats -> per-channel scale/shift for e and h
// ---------------------------------------------------------------------------
__global__ __launch_bounds__(256)
void k3_stats(const float* __restrict__ epart, const float* __restrict__ hacc,
              const float* __restrict__ gamma_e, const float* __restrict__ beta_e,
              const float* __restrict__ gamma_h, const float* __restrict__ beta_h,
              float* __restrict__ coefs)
{
    __shared__ float rs[256], rq[256];
    int c = blockIdx.x, tid = threadIdx.x;
    float s = 0, q = 0;
    if (c < HH) {
        for (int r = tid; r < NBI; r += 256) {
            s += epart[(size_t)r*2*HH + c];
            q += epart[(size_t)r*2*HH + HH + c];
        }
    } else {
        int hh = c - HH;
        for (int r = tid; r < NBI; r += 256) {
            float v = hacc[r*HH + hh];
            s += v; q += v*v;
        }
    }
    rs[tid] = s; rq[tid] = q;
    __syncthreads();
    for (int off = 128; off > 0; off >>= 1) {
        if (tid < off) { rs[tid] += rs[tid+off]; rq[tid] += rq[tid+off]; }
        __syncthreads();
    }
    if (tid == 0) {
        float n = (c < HH) ? (float)NE : (float)NBI;
        float mean = rs[0] / n;
        float var  = rq[0] / n - mean*mean;
        int hh; float g, be;
        if (c < HH) { hh = c;      g = gamma_e[hh]; be = beta_e[hh]; }
        else        { hh = c - HH; g = gamma_h[hh]; be = beta_h[hh]; }
        float scale = g * rsqrtf(var + BN_EPS);
        float shift = be - mean*scale;
        if (c < HH) { coefs[hh]        = scale; coefs[HH + hh]   = shift; }
        else        { coefs[2*HH + hh] = scale; coefs[3*HH + hh] = shift; }
    }
}

// ---------------------------------------------------------------------------
// K4: out1 = e + relu(bn(e_new)), reading the f16 fragment-permuted stash
// (first 256B of each 512B out1 row) through an LDS re-permute.
// One block per 64-row tile (4096 tiles). Also (first blocks) h and x outs.
// nt loads for the stash (never re-read), nt stores for out1 (never re-read).
// LDS row stride = 144 shorts (288B): r and r+1 land 8 banks apart -> <=4-way.
// ---------------------------------------------------------------------------
__global__ __launch_bounds__(256)
void k4_eout(const float* __restrict__ e, const float* __restrict__ coefs,
             const float* __restrict__ h, const float* __restrict__ x,
             const float* __restrict__ hacc, const float* __restrict__ xupd,
             const float* __restrict__ cp,
             float* __restrict__ out0, float* __restrict__ out2,
             float* __restrict__ out1)
{
    __shared__ unsigned short s_t[64*144];   // 18432 B
    int tid = threadIdx.x;
    int gid = blockIdx.x*256 + tid;
    if (gid < NBI*HH) {
        int hh = gid & 127;
        float v = hacc[gid]*coefs[2*HH + hh] + coefs[3*HH + hh];
        out0[gid] = h[gid] + fmaxf(v, 0.f);
        if (gid < NBI*2) out2[gid] = x[gid] + cp[0]*xupd[gid];
    }

    size_t r0 = (size_t)blockIdx.x * 64;
    const uintx4* sp = (const uintx4*)out1;
    #pragma unroll
    for (int it = 0; it < 4; ++it) {
        int rr = it*16 + (tid >> 4);
        int sg = tid & 15;
        uintx4 v = __builtin_nontemporal_load(&sp[(r0 + rr)*32 + sg]);
        *(uintx4*)(s_t + rr*144 + sg*8) = v;
    }
    __syncthreads();

    const float4* e4  = (const float4*)e;
    floatx4* o4       = (floatx4*)out1;
    const float4* sc4 = (const float4*)coefs;        // scale_e
    const float4* sh4 = (const float4*)(coefs + HH); // shift_e
    #pragma unroll
    for (int k = 0; k < 8; ++k) {
        int f  = k*256 + tid;        // 0..2047 float4s in tile
        int r  = f >> 5;
        int c4 = f & 31;
        size_t gi = (r0 + r)*32 + c4;
        float4 ev = e4[gi];
        float4 sc = sc4[c4], sh = sh4[c4];
        const unsigned short* row = s_t + r*144;
        int cc = c4*4;
        int pb = (cc & 15)*8 + (cc >> 4);   // p = (hh&15)*8 + (hh>>4)
        float4 en;
        en.x = h2f(row[pb]);
        en.y = h2f(row[pb + 8]);
        en.z = h2f(row[pb + 16]);
        en.w = h2f(row[pb + 24]);
        floatx4 rr;
        rr.x = ev.x + fmaxf(en.x*sc.x + sh.x, 0.f);
        rr.y = ev.y + fmaxf(en.y*sc.y + sh.y, 0.f);
        rr.z = ev.z + fmaxf(en.z*sc.z + sh.z, 0.f);
        rr.w = ev.w + fmaxf(en.w*sc.w + sh.w, 0.f);
        __builtin_nontemporal_store(rr, &o4[gi]);
    }
}

// ---------------------------------------------------------------------------
extern "C" void kernel_launch(void* const* d_in, const int* in_sizes, int n_in,
                              void* d_out, int out_size, void* d_ws, size_t ws_size,
                              hipStream_t stream)
{
    (void)in_sizes; (void)n_in; (void)out_size; (void)ws_size;
    const float* h     = (const float*)d_in[0];
    const float* e     = (const float*)d_in[1];
    const float* x     = (const float*)d_in[2];
    const int*   graph = (const int*)d_in[3];
    const float* Uw = (const float*)d_in[4];
    const float* Ub = (const float*)d_in[5];
    const float* Vw = (const float*)d_in[6];
    const float* Vb = (const float*)d_in[7];
    const float* Aw = (const float*)d_in[8];
    const float* Ab = (const float*)d_in[9];
    const float* Bw = (const float*)d_in[10];
    const float* Bbv = (const float*)d_in[11];
    const float* Cw = (const float*)d_in[12];
    const float* Cb = (const float*)d_in[13];
    const float* dw = (const float*)d_in[14];
    const float* db = (const float*)d_in[15];
    const float* ew = (const float*)d_in[16];
    const float* eb = (const float*)d_in[17];
    const float* c  = (const float*)d_in[18];
    const float* gamma_h = (const float*)d_in[19];
    const float* beta_h  = (const float*)d_in[20];
    const float* gamma_e = (const float*)d_in[21];
    const float* beta_e  = (const float*)d_in[22];

    float* out0 = (float*)d_out;
    float* out1 = out0 + NBI*HH;
    float* out2 = out1 + (size_t)NE*HH;

    float* ws    = (float*)d_ws;
    float* Uh    = ws;                      // NBI*HH
    float* Bh    = Uh + NBI*HH;             // NBI*HH
    float* avp   = Bh + NBI*HH;             // NBI*256 (A/V fragment-permuted)
    float* hacc  = avp + (size_t)NBI*256;   // NBI*HH
    float* epart = hacc + NBI*HH;           // NBI*2*HH
    float* xupd  = epart + (size_t)NBI*2*HH;
    float* coefs = xupd + NBI*2;
    unsigned short* cwp = (unsigned short*)(coefs + 4*HH);  // 16384 f16

    k1_lin4<<<NBI, 128, 0, stream>>>(h, Uw, Ub, Vw, Vb, Aw, Ab, Bw, Bbv, Cw,
                                     Uh, Bh, avp, cwp);
    k2_main<<<NBI, 256, 0, stream>>>(e, x, graph, cwp, Cb, dw, db, ew, eb,
                                     Uh, Bh, avp, (uintx4*)out1,
                                     epart, hacc, xupd);
    k3_stats<<<2*HH, 256, 0, stream>>>(epart, hacc, gamma_e, beta_e,
                                       gamma_h, beta_h, coefs);
    k4_eout<<<NE/64, 256, 0, stream>>>(e, coefs, h, x, hacc, xupd, c,
                                       out0, out2, out1);
}